// Round 27
// baseline (78.121 us; speedup 1.0000x reference)
//
#include <hip/hip_runtime.h>
#include <hip/hip_bf16.h>

typedef __attribute__((ext_vector_type(2)))  float f32x2;
typedef __attribute__((ext_vector_type(4)))  float f32x4;
typedef __attribute__((ext_vector_type(16))) float f32x16;
typedef __attribute__((ext_vector_type(8)))  short s16x8;
typedef __attribute__((ext_vector_type(2)))  unsigned int u32x2;
typedef __attribute__((ext_vector_type(4)))  unsigned int u32x4;
typedef __attribute__((ext_vector_type(2)))  int i32x2;

#define D_MODEL 1024
#define D_HEAD  64
#define SEQ_T   4096

__device__ __forceinline__ unsigned short f2bf(float f) {
    unsigned int u = __float_as_uint(f);
    u += 0x7fffu + ((u >> 16) & 1u);
    return (unsigned short)(u >> 16);
}

__device__ __forceinline__ unsigned int cvtpk_bf16(float lo, float hi) {
    unsigned int r;
    asm("v_cvt_pk_bf16_f32 %0, %1, %2" : "=v"(r) : "v"(lo), "v"(hi));
    return r;
}

// raw 2^x (single v_exp_f32).  Scores are computed in log2 domain (log2e
// folded into the q pre-scale), so no per-element multiply is needed.
__device__ __forceinline__ float ex2(float x) {
#if __has_builtin(__builtin_amdgcn_exp2f)
    return __builtin_amdgcn_exp2f(x);
#else
    return exp2f(x);
#endif
}

// lane l <-> lane l^32 exchange.  Returns BOTH post-exchange words: per lane
// {r0, r1} == {x[l], x[l^32]} (order may be lane-dependent).  Consumers use
// order-agnostic ops (fmax/add) or r0^r1^x for the partner.  SSA builtin ->
// distinct result registers, no aliasing.  PROVEN round 10/11/12.
__device__ __forceinline__ void halfswap(unsigned int x,
                                         unsigned int& r0, unsigned int& r1) {
#if __has_builtin(__builtin_amdgcn_permlane32_swap)
    i32x2 r = __builtin_amdgcn_permlane32_swap((int)x, (int)x, false, false);
    r0 = (unsigned int)r[0];
    r1 = (unsigned int)r[1];
#else
    r0 = x;
    r1 = (unsigned int)__shfl_xor((int)x, 32);       // proven fallback
#endif
}

// async global->LDS 16B DMA (per-lane global src, wave-linear LDS dest:
// base + lane*16).  Falls back to reg round-trip with identical addressing.
__device__ __forceinline__ void gload_lds16(const unsigned short* g,
                                            unsigned short* l) {
#if __has_builtin(__builtin_amdgcn_global_load_lds)
    __builtin_amdgcn_global_load_lds(
        (const __attribute__((address_space(1))) void*)g,
        (__attribute__((address_space(3))) void*)l, 16, 0, 0);
#else
    const int lane = (int)(threadIdx.x & 63);
    *(u32x4*)((char*)l + lane * 16) = *(const u32x4*)g;
#endif
}

__device__ __forceinline__ f32x4 mfma16(s16x8 a, s16x8 b, f32x4 c) {
    return __builtin_amdgcn_mfma_f32_16x16x32_bf16(a, b, c, 0, 0, 0);
}
__device__ __forceinline__ f32x16 mfma32(s16x8 a, s16x8 b, f32x16 c) {
    return __builtin_amdgcn_mfma_f32_32x32x16_bf16(a, b, c, 0, 0, 0);
}

// ---------------------------------------------------------------------------
// Kernel 0: weights [1024][64] f32 (q,k,v) -> wT [192][1024] bf16 (transposed)
// ---------------------------------------------------------------------------
__global__ __launch_bounds__(256) void wconv_kernel(
    const float* __restrict__ wq, const float* __restrict__ wk,
    const float* __restrict__ wv, unsigned short* __restrict__ wT)
{
    int idx = blockIdx.x * 256 + threadIdx.x;        // [0, 3*65536)
    int mat = idx >> 16;
    int rem = idx & 65535;
    int k = rem >> 6, n = rem & 63;
    const float* w = (mat == 0) ? wq : (mat == 1) ? wk : wv;
    wT[(size_t)(mat * 64 + n) * D_MODEL + k] = f2bf(w[rem]);
}

// ---------------------------------------------------------------------------
// Kernel 1: fused QKV projection — WHOLE-X-IN-LDS GEMM, BM=64, grid 512.
// Round 27: remove x from the per-step barrier dependency entirely (6 qkv
// variants pinned at 40-47us shared one invariant: per-step HBM-latency-
// exposed x delivery).  Prologue streams the block's FULL 64x1024 x tile
// (256KB fp32) in one burst -> cvt bf16 -> LDS in CHUNK-MAJOR order
// xt[c][row][8] (COMPUTE reads are 16B-stride across rows = conflict-free,
// no swizzle).  Main loop touches only L2-resident weights (r25 machinery:
// gload_lds w=16, linear [96][64], pre-swizzled source col16^=(row&7),
// XOR-swizzled ds_read).  Barrier drain now waits on 3 L2-hit DMAs only.
// LDS: x 128KB + w 2x12KB = 152KB -> 1 block/CU.
// Block remap mb=bid&255, nb=bid>>8: same-mb nb-pair lands on same XCD
// (bid%8 equal) for x L2 reuse on the second pass.
// Epilogue writes fragment-tiled K/V; q pre-scaled by log2e/8.
// ---------------------------------------------------------------------------
__global__ __launch_bounds__(256, 1) void qkv_kernel(
    const float* __restrict__ x,
    const float* __restrict__ bq, const float* __restrict__ bk,
    const float* __restrict__ bv,
    const unsigned short* __restrict__ wT,
    unsigned short* __restrict__ q_ws, unsigned short* __restrict__ k_ws,
    unsigned short* __restrict__ vT_ws)
{
    __shared__ unsigned short xt[128 * 64 * 8];      // 128 KB: [chunk][row][8]
    __shared__ unsigned short wls[2][96 * 64];       // 2 x 12 KB  (152 KB tot)
    const int t = threadIdx.x;
    const int lane = t & 63, w = t >> 6;
    const int wr = w >> 1, wc = w & 1;
    const int lr = lane & 15, lg = lane >> 4;
    const int mb = (int)blockIdx.x & 255, nb = (int)blockIdx.x >> 8;

    // weight DMA: wave fills rows i*8..i*8+7 for i = w*3+j (j=0..2);
    // lane covers row i*8+(lane>>3), col16 pre-swizzled (lane&7)^(lane>>3).
    const unsigned short* wgbase = wT
        + (size_t)(nb * 96 + (lane >> 3)) * D_MODEL
        + ((lane & 7) ^ (lane >> 3)) * 8;

#define WLOAD(BUF, K0) do {                                                    \
    _Pragma("unroll") for (int j = 0; j < 3; ++j) {                            \
        const int i = w * 3 + j;                                               \
        gload_lds16(wgbase + (size_t)(i * 8) * D_MODEL + (K0),                 \
                    &wls[BUF][i * 512]);                                       \
    }                                                                          \
} while (0)

    // ---- prologue: whole x tile -> LDS (bf16, chunk-major) + first WLOAD --
    WLOAD(0, 0);
    {
        const int row = t >> 2;                      // 64 rows, 4 thr/row
        const float* xr = x + (size_t)(mb * 64 + row) * D_MODEL + (t & 3) * 256;
        for (int i = 0; i < 32; ++i) {               // 32 chunks of 8 elems
            f32x4 a0 = *(const f32x4*)(xr + i * 8);
            f32x4 a1 = *(const f32x4*)(xr + i * 8 + 4);
            u32x4 pv;
            pv[0] = cvtpk_bf16(a0[0], a0[1]);
            pv[1] = cvtpk_bf16(a0[2], a0[3]);
            pv[2] = cvtpk_bf16(a1[0], a1[1]);
            pv[3] = cvtpk_bf16(a1[2], a1[3]);
            const int c = (t & 3) * 32 + i;
            *(u32x4*)(xt + (c * 64 + row) * 8) = pv;
        }
    }

    f32x4 acc[2][3];
#pragma unroll
    for (int s = 0; s < 2; ++s)
#pragma unroll
        for (int c = 0; c < 3; ++c) acc[s][c] = (f32x4)0.0f;

#define COMPUTE(BUF, K0) do {                                                  \
    const char* WB = (const char*)&wls[BUF][0];                                \
    _Pragma("unroll") for (int ks = 0; ks < 2; ++ks) {                         \
        s16x8 af[2];                                                           \
        _Pragma("unroll") for (int sub = 0; sub < 2; ++sub) {                  \
            const int ch = ((K0) >> 3) + ks * 4 + lg;                          \
            const int rw = wr * 32 + sub * 16 + lr;                            \
            af[sub] = *(const s16x8*)(xt + (ch * 64 + rw) * 8);                \
        }                                                                      \
        _Pragma("unroll") for (int tc = 0; tc < 3; ++tc) {                     \
            const int rowR = wc * 48 + tc * 16 + lr;                           \
            const int cb = (ks * 64 + lg * 16) ^ ((rowR & 7) << 4);            \
            s16x8 bf = *(const s16x8*)(WB + rowR * 128 + cb);                  \
            acc[0][tc] = mfma16(af[0], bf, acc[0][tc]);                        \
            acc[1][tc] = mfma16(af[1], bf, acc[1][tc]);                        \
        }                                                                      \
    }                                                                          \
} while (0)

    __syncthreads();                                 // x tile + w tile 0 ready

    for (int step = 0; step < 16; ++step) {
        const int cur = step & 1;
        if (step + 1 < 16) WLOAD(cur ^ 1, (step + 1) * 64);
        COMPUTE(cur, step * 64);
        __syncthreads();                             // drains 3 L2-hit DMAs
    }

#undef WLOAD
#undef COMPUTE

    // epilogue: bias + dtype-split writes (K/V into fragment-tiled layouts)
#pragma unroll
    for (int sub = 0; sub < 2; ++sub)
#pragma unroll
        for (int tc = 0; tc < 3; ++tc) {
            int col = nb * 96 + wc * 48 + tc * 16 + lr;
            float bias = (col < 64) ? bq[col] : (col < 128) ? bk[col - 64] : bv[col - 128];
#pragma unroll
            for (int r = 0; r < 4; ++r) {
                int row = mb * 64 + wr * 32 + sub * 16 + lg * 4 + r;   // = b*4096 + t
                float v = acc[sub][tc][r] + bias;
                int bb = row >> 12, tt = row & 4095;
                int cc_ = tt >> 5;
                if (col < 64) {
                    // scale = 1/sqrt(64) * log2(e): softmax in exp2 domain
                    q_ws[(size_t)row * 64 + col] = f2bf(v * 0.18033688011112042f);
                } else if (col < 128) {
                    int kcol = col - 64;
                    int d = kcol >> 4, hi2 = (kcol >> 3) & 1, e = kcol & 7;
                    int l = (tt & 31) + 32 * hi2;
                    k_ws[(size_t)(((bb * 128 + cc_) * 4 + d) * 64 + l) * 8 + e] = f2bf(v);
                } else {
                    int h = col - 128;
                    int w32 = tt & 31;
                    int fb0 = (w32 >> 4) & 1, hi2 = (w32 >> 3) & 1, e = w32 & 7;
                    int f = ((h >> 5) << 1) | fb0;
                    int l = (h & 31) + 32 * hi2;
                    vT_ws[(size_t)(((bb * 128 + cc_) * 4 + f) * 64 + l) * 8 + e] = f2bf(v);
                }
            }
        }
}

// ---------------------------------------------------------------------------
// Kernel 2: causal flash attention, swapped-QK in-register softmax (32x32),
// exp2-domain.  Round-12 structure (grid 256, block=(b,p), q-tiles qb=p and
// qb=127-p sequentially = 129 KV-tiles/block, 16 waves, stride-16 KV split,
// K prefetched 1 tile ahead, V at use).
// K/V read from the fragment-tiled layouts -> every load is a fully-
// coalesced contiguous 1KB dwordx4 (round-18: attn 49 -> ~16us).
// ---------------------------------------------------------------------------
__global__ __launch_bounds__(1024, 4) void attn_kernel(
    const unsigned short* __restrict__ q_ws, const unsigned short* __restrict__ k_ws,
    const unsigned short* __restrict__ vT_ws, float* __restrict__ out)
{
    __shared__ float solds[8][32][66];               // 67.6 KiB
    __shared__ float sml[16][2][32];                 // 4 KiB
    const int lane = threadIdx.x & 63;
    const int w = threadIdx.x >> 6;                  // 0..15
    const int q = lane & 31;
    const int hi = lane >> 5;
    const int khalf = 4 * hi;
    // XCD-batch swizzle: batch = bits 1-2 of bid (pins K/V to an XCD pair).
    const int b = ((int)blockIdx.x & 7) >> 1;
    const int p = ((int)blockIdx.x >> 3) + (((int)blockIdx.x & 1) << 5);  // 0..63

#define PUBLISH(SLOT) do {                                                     \
    _Pragma("unroll") for (int i = 0; i < 16; ++i) {                           \
        int d = (i & 3) + 8 * (i >> 2) + khalf;                                \
        solds[SLOT][q][d] = o0[i];                                             \
        solds[SLOT][q][d + 32] = o1[i];                                        \
    }                                                                          \
    if (!hi) { sml[w][0][q] = m; sml[w][1][q] = lsum; }                        \
} while (0)

#define MERGE(SLOT, PW) do {                                                   \
    float mp = sml[PW][0][q], lp = sml[PW][1][q];                              \
    float M = fmaxf(m, mp);                                                    \
    float e = ex2(m - M), ep = ex2(mp - M);                                    \
    m = M; lsum = lsum * e + lp * ep;                                          \
    _Pragma("unroll") for (int i = 0; i < 16; ++i) {                           \
        int d = (i & 3) + 8 * (i >> 2) + khalf;                                \
        o0[i] = o0[i] * e + solds[SLOT][q][d] * ep;                            \
        o1[i] = o1[i] * e + solds[SLOT][q][d + 32] * ep;                       \
    }                                                                          \
} while (0)

    // fragment-tiled bases: 2048 elements (4 KB) per KV-tile
    const unsigned short* kt = k_ws + (size_t)(b * 128) * 2048;
    const unsigned short* vt = vT_ws + (size_t)(b * 128) * 2048;
    const int lane8 = lane * 8;

    for (int half = 0; half < 2; ++half) {
        const int qb = (half == 0) ? p : 127 - p;
        const int q0 = SEQ_T - 32 * (qb + 1);
        const int ntiles = (q0 >> 5) + 1;

        const unsigned short* qrow = q_ws + ((size_t)(b * SEQ_T + q0 + q)) * 64 + hi * 8;
        s16x8 qf[4];
#pragma unroll
        for (int d = 0; d < 4; ++d) qf[d] = *(const s16x8*)(qrow + d * 16);

        f32x16 o0 = (f32x16)0.0f, o1 = (f32x16)0.0f;
        float m = -1e30f, lsum = 0.0f;

        int c = w;
        if (c < ntiles) {
            s16x8 kf[4];
            {
                const unsigned short* kp = kt + (size_t)c * 2048 + lane8;
#pragma unroll
                for (int d = 0; d < 4; ++d) kf[d] = *(const s16x8*)(kp + d * 512);
            }
            for (; c < ntiles; c += 16) {
                const int kv = c << 5;
                // ---- S^T = K Q^T (log2 domain) ----
                f32x16 s = (f32x16)0.0f;
                __builtin_amdgcn_s_setprio(1);
#pragma unroll
                for (int d = 0; d < 4; ++d) s = mfma32(kf[d], qf[d], s);
                __builtin_amdgcn_s_setprio(0);
                // ---- prefetch next K tile (stride 16), coalesced ----
                {
                    const int cn = (c + 16 < ntiles) ? c + 16 : 0;
                    const unsigned short* kp = kt + (size_t)cn * 2048 + lane8;
#pragma unroll
                    for (int d = 0; d < 4; ++d) kf[d] = *(const s16x8*)(kp + d * 512);
                }
                // ---- V fragments (coalesced; in flight during softmax) ----
                const unsigned short* vp = vt + (size_t)c * 2048 + lane8;
                s16x8 vf00 = *(const s16x8*)(vp);
                s16x8 vf01 = *(const s16x8*)(vp + 512);
                s16x8 vf10 = *(const s16x8*)(vp + 1024);
                s16x8 vf11 = *(const s16x8*)(vp + 1536);
                // ---- causal mask (diagonal tile only) ----
                if (kv + 32 > q0) {
                    const int qg = q0 + q;
#pragma unroll
                    for (int i = 0; i < 16; ++i) {
                        int kk = kv + (i & 3) + 8 * (i >> 2) + khalf;
                        if (kk > qg) s[i] = -1e30f;
                    }
                }
                // ---- row max: tree + half-exchange (order-agnostic) ----
                float t0, t1;
                t0 = fmaxf(s[0], s[1]);   t1 = fmaxf(s[2], s[3]);   t0 = fmaxf(t0, t1);
                t1 = fmaxf(s[4], s[5]);   t1 = fmaxf(t1, fmaxf(s[6], s[7]));
                float t2 = fmaxf(fmaxf(s[8], s[9]), fmaxf(s[10], s[11]));
                float t3 = fmaxf(fmaxf(s[12], s[13]), fmaxf(s[14], s[15]));
                float mx = fmaxf(fmaxf(t0, t1), fmaxf(t2, t3));
                {
                    unsigned int r0, r1;
                    halfswap(__float_as_uint(mx), r0, r1);
                    mx = fmaxf(__uint_as_float(r0), __uint_as_float(r1));
                }
                const float mnew = fmaxf(m, mx);
                const float corr = ex2(m - mnew);
                m = mnew;
                // ---- P = 2^(S - m), row sum ----
                float rs = 0.0f;
#pragma unroll
                for (int i = 0; i < 16; ++i) {
                    float pv = ex2(s[i] - mnew);
                    s[i] = pv;
                    rs += pv;
                }
                {
                    unsigned int r0, r1;
                    halfswap(__float_as_uint(rs), r0, r1);
                    rs = __uint_as_float(r0) + __uint_as_float(r1);
                }
                lsum = lsum * corr + rs;
#pragma unroll
                for (int i = 0; i < 16; ++i) { o0[i] *= corr; o1[i] *= corr; }
                // ---- pack P -> B-fragments (cvt_pk; partner via r0^r1^own) ----
                unsigned int cc[8], pc[8];
#pragma unroll
                for (int i = 0; i < 8; ++i) cc[i] = cvtpk_bf16(s[2 * i], s[2 * i + 1]);
#pragma unroll
                for (int i = 0; i < 8; ++i) {
                    unsigned int r0, r1;
                    halfswap(cc[i], r0, r1);
                    pc[i] = r0 ^ r1 ^ cc[i];         // partner word, any convention
                }
                u32x4 w0, w1;
                w0[0] = hi ? pc[2] : cc[0]; w0[1] = hi ? pc[3] : cc[1];
                w0[2] = hi ? cc[2] : pc[0]; w0[3] = hi ? cc[3] : pc[1];
                w1[0] = hi ? pc[6] : cc[4]; w1[1] = hi ? pc[7] : cc[5];
                w1[2] = hi ? cc[6] : pc[4]; w1[3] = hi ? cc[7] : pc[5];
                s16x8 pb0 = __builtin_bit_cast(s16x8, w0);
                s16x8 pb1 = __builtin_bit_cast(s16x8, w1);
                // ---- O^T += V^T P^T ----
                __builtin_amdgcn_s_setprio(1);
                o0 = mfma32(vf00, pb0, o0);
                o0 = mfma32(vf01, pb1, o0);
                o1 = mfma32(vf10, pb0, o1);
                o1 = mfma32(vf11, pb1, o1);
                __builtin_amdgcn_s_setprio(0);
            }
        }

        // ---- cascade combine: 16 -> 8 -> 4 -> 1 ----
        if (w >= 8) PUBLISH(w - 8);
        __syncthreads();
        if (w < 8) MERGE(w, w + 8);
        __syncthreads();
        if (w >= 4 && w < 8) PUBLISH(w - 4);
        __syncthreads();
        if (w < 4) { MERGE(w, w + 4); PUBLISH(w); }
        __syncthreads();
        // ---- final: 1024 threads, 2 outputs each ----
        {
            const int qq = (int)threadIdx.x >> 5;
            const int dd = ((int)threadIdx.x & 31) * 2;
            float M = -1e30f;
#pragma unroll
            for (int ww = 0; ww < 4; ++ww) M = fmaxf(M, sml[ww][0][qq]);
            float L = 0.0f, O0 = 0.0f, O1 = 0.0f;
#pragma unroll
            for (int ww = 0; ww < 4; ++ww) {
                float e = ex2(sml[ww][0][qq] - M);
                L += sml[ww][1][qq] * e;
                O0 += solds[ww][qq][dd] * e;
                O1 += solds[ww][qq][dd + 1] * e;
            }
            f32x2 res; res[0] = O0 / L; res[1] = O1 / L;
            *(f32x2*)(out + ((size_t)(b * SEQ_T + q0 + qq)) * 64 + dd) = res;
        }
        __syncthreads();                             // solds reused by next half
    }
#undef PUBLISH
#undef MERGE
}

// ---------------------------------------------------------------------------
extern "C" void kernel_launch(void* const* d_in, const int* in_sizes, int n_in,
                              void* d_out, int out_size, void* d_ws, size_t ws_size,
                              hipStream_t stream) {
    const float* x  = (const float*)d_in[0];
    const float* wq = (const float*)d_in[1];
    const float* bq = (const float*)d_in[2];
    const float* wk = (const float*)d_in[3];
    const float* bk = (const float*)d_in[4];
    const float* wv = (const float*)d_in[5];
    const float* bv = (const float*)d_in[6];
    float* out = (float*)d_out;

    char* ws = (char*)d_ws;
    unsigned short* wT    = (unsigned short*)(ws);                       // 384 KiB
    unsigned short* q_ws  = (unsigned short*)(ws + 393216);              // 2 MiB
    unsigned short* k_ws  = (unsigned short*)(ws + 393216 + 2097152);    // 2 MiB (tiled)
    unsigned short* vT_ws = (unsigned short*)(ws + 393216 + 2 * 2097152);// 2 MiB (tiled)

    wconv_kernel<<<dim3(768), dim3(256), 0, stream>>>(wq, wk, wv, wT);
    qkv_kernel<<<dim3(512), dim3(256), 0, stream>>>(x, bq, bk, bv, wT, q_ws, k_ws, vT_ws);
    attn_kernel<<<dim3(256), dim3(1024), 0, stream>>>(q_ws, k_ws, vT_ws, out);
}

// Round 28
// 58.144 us; speedup vs baseline: 1.3436x; 1.3436x over previous
//
#include <hip/hip_runtime.h>
#include <hip/hip_bf16.h>

typedef __attribute__((ext_vector_type(2)))  float f32x2;
typedef __attribute__((ext_vector_type(4)))  float f32x4;
typedef __attribute__((ext_vector_type(16))) float f32x16;
typedef __attribute__((ext_vector_type(8)))  short s16x8;
typedef __attribute__((ext_vector_type(4)))  unsigned int u32x4;
typedef __attribute__((ext_vector_type(2)))  int i32x2;

#define D_MODEL 1024
#define D_HEAD  64
#define SEQ_T   4096

__device__ __forceinline__ unsigned short f2bf(float f) {
    unsigned int u = __float_as_uint(f);
    u += 0x7fffu + ((u >> 16) & 1u);
    return (unsigned short)(u >> 16);
}

__device__ __forceinline__ unsigned int cvtpk_bf16(float lo, float hi) {
    unsigned int r;
    asm("v_cvt_pk_bf16_f32 %0, %1, %2" : "=v"(r) : "v"(lo), "v"(hi));
    return r;
}

// raw 2^x (single v_exp_f32).  Scores are computed in log2 domain (log2e
// folded into the q pre-scale), so no per-element multiply is needed.
__device__ __forceinline__ float ex2(float x) {
#if __has_builtin(__builtin_amdgcn_exp2f)
    return __builtin_amdgcn_exp2f(x);
#else
    return exp2f(x);
#endif
}

// lane l <-> lane l^32 exchange.  Returns BOTH post-exchange words: per lane
// {r0, r1} == {x[l], x[l^32]} (order may be lane-dependent).  Consumers use
// order-agnostic ops (fmax/add) or r0^r1^x for the partner.  SSA builtin ->
// distinct result registers, no aliasing.  PROVEN round 10/11/12.
__device__ __forceinline__ void halfswap(unsigned int x,
                                         unsigned int& r0, unsigned int& r1) {
#if __has_builtin(__builtin_amdgcn_permlane32_swap)
    i32x2 r = __builtin_amdgcn_permlane32_swap((int)x, (int)x, false, false);
    r0 = (unsigned int)r[0];
    r1 = (unsigned int)r[1];
#else
    r0 = x;
    r1 = (unsigned int)__shfl_xor((int)x, 32);       // proven fallback
#endif
}

__device__ __forceinline__ f32x4 mfma16(s16x8 a, s16x8 b, f32x4 c) {
    return __builtin_amdgcn_mfma_f32_16x16x32_bf16(a, b, c, 0, 0, 0);
}
__device__ __forceinline__ f32x16 mfma32(s16x8 a, s16x8 b, f32x16 c) {
    return __builtin_amdgcn_mfma_f32_32x32x16_bf16(a, b, c, 0, 0, 0);
}

// ---------------------------------------------------------------------------
// Kernel 0: weights [1024][64] f32 (q,k,v) -> wT [192][1024] bf16 (transposed)
// ---------------------------------------------------------------------------
__global__ __launch_bounds__(256) void wconv_kernel(
    const float* __restrict__ wq, const float* __restrict__ wk,
    const float* __restrict__ wv, unsigned short* __restrict__ wT)
{
    int idx = blockIdx.x * 256 + threadIdx.x;        // [0, 3*65536)
    int mat = idx >> 16;
    int rem = idx & 65535;
    int k = rem >> 6, n = rem & 63;
    const float* w = (mat == 0) ? wq : (mat == 1) ? wk : wv;
    wT[(size_t)(mat * 64 + n) * D_MODEL + k] = f2bf(w[rem]);
}

// ---------------------------------------------------------------------------
// Kernel 1: fused QKV projection — 2-phase LDS GEMM (banked best config,
// round 18: total 58.0us).  STRIDES KEEP 16B ROW ALIGNMENT: x [64][68] f32,
// wT [96][72] bf16.  q pre-scaled by log2e/8.
// K and V written in MFMA-FRAGMENT-TILED layout so the attention kernel's
// loads are fully coalesced:
//   kt[((b*128 + c)*4 + d)*512 + l*8 + e] = K[b][c*32+(l&31)][d*16+(l>>5)*8+e]
//   vt[((b*128 + c)*4 + f)*512 + l*8 + e] =
//        V[b][(f>>1)*32+(l&31)][c*32+(f&1)*16+(l>>5)*8+e]
// ---------------------------------------------------------------------------
#define XSTR 68
#define WSTR 72
__global__ __launch_bounds__(256, 2) void qkv_kernel(
    const float* __restrict__ x,
    const float* __restrict__ bq, const float* __restrict__ bk,
    const float* __restrict__ bv,
    const unsigned short* __restrict__ wT,
    unsigned short* __restrict__ q_ws, unsigned short* __restrict__ k_ws,
    unsigned short* __restrict__ vT_ws)
{
    __shared__ float xs[2][64 * XSTR];               // 2 x 17408 B
    __shared__ unsigned short wls[2][96 * WSTR];     // 2 x 13824 B (61 KiB)
    const int t = threadIdx.x;
    const int lane = t & 63, w = t >> 6;
    const int wr = w >> 1, wc = w & 1;
    const int lr = lane & 15, lg = lane >> 4;
    const int mb = (int)blockIdx.x >> 1, nb = (int)blockIdx.x & 1;

    const float* xsrc = x + (size_t)(mb * 64 + (t >> 4)) * D_MODEL + (t & 15) * 4;
    const unsigned short* wsrc = wT + (size_t)(nb * 96 + (t >> 3)) * D_MODEL + (t & 7) * 8;

    f32x4 acc[2][3];
#pragma unroll
    for (int s = 0; s < 2; ++s)
#pragma unroll
        for (int c = 0; c < 3; ++c) acc[s][c] = (f32x4)0.0f;

    f32x4 xreg[4];
    u32x4 wreg[3];

#define GLOAD(K0) do {                                                         \
    _Pragma("unroll") for (int j = 0; j < 4; ++j)                              \
        xreg[j] = *(const f32x4*)(xsrc + (size_t)j * 16 * D_MODEL + (K0));     \
    _Pragma("unroll") for (int j = 0; j < 3; ++j)                              \
        wreg[j] = *(const u32x4*)(wsrc + (size_t)j * 32 * D_MODEL + (K0));     \
} while (0)

#define DSWRITE(BUF) do {                                                      \
    float* XB = &xs[BUF][0]; unsigned short* WB = &wls[BUF][0];                \
    _Pragma("unroll") for (int j = 0; j < 4; ++j)                              \
        *(f32x4*)(XB + ((t >> 4) + j * 16) * XSTR + (t & 15) * 4) = xreg[j];   \
    _Pragma("unroll") for (int j = 0; j < 3; ++j)                              \
        *(u32x4*)(WB + ((t >> 3) + j * 32) * WSTR + (t & 7) * 8) = wreg[j];    \
} while (0)

#define COMPUTE(BUF) do {                                                      \
    const float* XB = &xs[BUF][0]; const unsigned short* WB = &wls[BUF][0];    \
    _Pragma("unroll") for (int ks = 0; ks < 2; ++ks) {                         \
        s16x8 af[2];                                                           \
        _Pragma("unroll") for (int sub = 0; sub < 2; ++sub) {                  \
            const float* ap = XB + (wr * 32 + sub * 16 + lr) * XSTR + ks * 32 + lg * 8; \
            f32x4 a0 = *(const f32x4*)ap, a1 = *(const f32x4*)(ap + 4);        \
            u32x4 pk;                                                          \
            pk[0] = cvtpk_bf16(a0[0], a0[1]); pk[1] = cvtpk_bf16(a0[2], a0[3]);\
            pk[2] = cvtpk_bf16(a1[0], a1[1]); pk[3] = cvtpk_bf16(a1[2], a1[3]);\
            af[sub] = __builtin_bit_cast(s16x8, pk);                           \
        }                                                                      \
        _Pragma("unroll") for (int tc = 0; tc < 3; ++tc) {                     \
            s16x8 bf = *(const s16x8*)(WB + (wc * 48 + tc * 16 + lr) * WSTR + ks * 32 + lg * 8); \
            acc[0][tc] = mfma16(af[0], bf, acc[0][tc]);                        \
            acc[1][tc] = mfma16(af[1], bf, acc[1][tc]);                        \
        }                                                                      \
    }                                                                          \
} while (0)

    // prologue: stage tile 0, issue tile 1
    GLOAD(0);
    DSWRITE(0);
    GLOAD(64);
    __syncthreads();

    for (int step = 0; step < 16; ++step) {
        const int cur = step & 1;
        if (step + 1 < 16) DSWRITE(cur ^ 1);         // write next tile (regs ready)
        if (step + 2 < 16) GLOAD((step + 2) * 64);   // issue loads 2 steps ahead
        COMPUTE(cur);
        __syncthreads();                             // one barrier per K-step
    }

#undef GLOAD
#undef DSWRITE
#undef COMPUTE

    // epilogue: bias + dtype-split writes (K/V into fragment-tiled layouts)
#pragma unroll
    for (int sub = 0; sub < 2; ++sub)
#pragma unroll
        for (int tc = 0; tc < 3; ++tc) {
            int col = nb * 96 + wc * 48 + tc * 16 + lr;
            float bias = (col < 64) ? bq[col] : (col < 128) ? bk[col - 64] : bv[col - 128];
#pragma unroll
            for (int r = 0; r < 4; ++r) {
                int row = mb * 64 + wr * 32 + sub * 16 + lg * 4 + r;   // = b*4096 + t
                float v = acc[sub][tc][r] + bias;
                int bb = row >> 12, tt = row & 4095;
                int cc_ = tt >> 5;
                if (col < 64) {
                    // scale = 1/sqrt(64) * log2(e): softmax in exp2 domain
                    q_ws[(size_t)row * 64 + col] = f2bf(v * 0.18033688011112042f);
                } else if (col < 128) {
                    int kcol = col - 64;
                    int d = kcol >> 4, hi2 = (kcol >> 3) & 1, e = kcol & 7;
                    int l = (tt & 31) + 32 * hi2;
                    k_ws[(size_t)(((bb * 128 + cc_) * 4 + d) * 64 + l) * 8 + e] = f2bf(v);
                } else {
                    int h = col - 128;
                    int w32 = tt & 31;
                    int fb0 = (w32 >> 4) & 1, hi2 = (w32 >> 3) & 1, e = w32 & 7;
                    int f = ((h >> 5) << 1) | fb0;
                    int l = (h & 31) + 32 * hi2;
                    vT_ws[(size_t)(((bb * 128 + cc_) * 4 + f) * 64 + l) * 8 + e] = f2bf(v);
                }
            }
        }
}

// ---------------------------------------------------------------------------
// Kernel 2: causal flash attention, swapped-QK in-register softmax (32x32),
// exp2-domain.  Grid 256, block=(b,p): q-tiles qb=p and qb=127-p processed
// sequentially = exactly 129 KV-tiles/block (placement-independent balance).
// 16 waves, stride-16 KV split, K prefetched 1 tile ahead, V at use.
// K/V read from the fragment-tiled layouts -> every load is a fully-
// coalesced contiguous 1KB dwordx4 (round-18: attn 49 -> ~16us).
// ---------------------------------------------------------------------------
__global__ __launch_bounds__(1024, 4) void attn_kernel(
    const unsigned short* __restrict__ q_ws, const unsigned short* __restrict__ k_ws,
    const unsigned short* __restrict__ vT_ws, float* __restrict__ out)
{
    __shared__ float solds[8][32][66];               // 67.6 KiB
    __shared__ float sml[16][2][32];                 // 4 KiB
    const int lane = threadIdx.x & 63;
    const int w = threadIdx.x >> 6;                  // 0..15
    const int q = lane & 31;
    const int hi = lane >> 5;
    const int khalf = 4 * hi;
    // XCD-batch swizzle: batch = bits 1-2 of bid (pins K/V to an XCD pair).
    const int b = ((int)blockIdx.x & 7) >> 1;
    const int p = ((int)blockIdx.x >> 3) + (((int)blockIdx.x & 1) << 5);  // 0..63

#define PUBLISH(SLOT) do {                                                     \
    _Pragma("unroll") for (int i = 0; i < 16; ++i) {                           \
        int d = (i & 3) + 8 * (i >> 2) + khalf;                                \
        solds[SLOT][q][d] = o0[i];                                             \
        solds[SLOT][q][d + 32] = o1[i];                                        \
    }                                                                          \
    if (!hi) { sml[w][0][q] = m; sml[w][1][q] = lsum; }                        \
} while (0)

#define MERGE(SLOT, PW) do {                                                   \
    float mp = sml[PW][0][q], lp = sml[PW][1][q];                              \
    float M = fmaxf(m, mp);                                                    \
    float e = ex2(m - M), ep = ex2(mp - M);                                    \
    m = M; lsum = lsum * e + lp * ep;                                          \
    _Pragma("unroll") for (int i = 0; i < 16; ++i) {                           \
        int d = (i & 3) + 8 * (i >> 2) + khalf;                                \
        o0[i] = o0[i] * e + solds[SLOT][q][d] * ep;                            \
        o1[i] = o1[i] * e + solds[SLOT][q][d + 32] * ep;                       \
    }                                                                          \
} while (0)

    // fragment-tiled bases: 2048 elements (4 KB) per KV-tile
    const unsigned short* kt = k_ws + (size_t)(b * 128) * 2048;
    const unsigned short* vt = vT_ws + (size_t)(b * 128) * 2048;
    const int lane8 = lane * 8;

    for (int half = 0; half < 2; ++half) {
        const int qb = (half == 0) ? p : 127 - p;
        const int q0 = SEQ_T - 32 * (qb + 1);
        const int ntiles = (q0 >> 5) + 1;

        const unsigned short* qrow = q_ws + ((size_t)(b * SEQ_T + q0 + q)) * 64 + hi * 8;
        s16x8 qf[4];
#pragma unroll
        for (int d = 0; d < 4; ++d) qf[d] = *(const s16x8*)(qrow + d * 16);

        f32x16 o0 = (f32x16)0.0f, o1 = (f32x16)0.0f;
        float m = -1e30f, lsum = 0.0f;

        int c = w;
        if (c < ntiles) {
            s16x8 kf[4];
            {
                const unsigned short* kp = kt + (size_t)c * 2048 + lane8;
#pragma unroll
                for (int d = 0; d < 4; ++d) kf[d] = *(const s16x8*)(kp + d * 512);
            }
            for (; c < ntiles; c += 16) {
                const int kv = c << 5;
                // ---- S^T = K Q^T (log2 domain) ----
                f32x16 s = (f32x16)0.0f;
                __builtin_amdgcn_s_setprio(1);
#pragma unroll
                for (int d = 0; d < 4; ++d) s = mfma32(kf[d], qf[d], s);
                __builtin_amdgcn_s_setprio(0);
                // ---- prefetch next K tile (stride 16), coalesced ----
                {
                    const int cn = (c + 16 < ntiles) ? c + 16 : 0;
                    const unsigned short* kp = kt + (size_t)cn * 2048 + lane8;
#pragma unroll
                    for (int d = 0; d < 4; ++d) kf[d] = *(const s16x8*)(kp + d * 512);
                }
                // ---- V fragments (coalesced; in flight during softmax) ----
                const unsigned short* vp = vt + (size_t)c * 2048 + lane8;
                s16x8 vf00 = *(const s16x8*)(vp);
                s16x8 vf01 = *(const s16x8*)(vp + 512);
                s16x8 vf10 = *(const s16x8*)(vp + 1024);
                s16x8 vf11 = *(const s16x8*)(vp + 1536);
                // ---- causal mask (diagonal tile only) ----
                if (kv + 32 > q0) {
                    const int qg = q0 + q;
#pragma unroll
                    for (int i = 0; i < 16; ++i) {
                        int kk = kv + (i & 3) + 8 * (i >> 2) + khalf;
                        if (kk > qg) s[i] = -1e30f;
                    }
                }
                // ---- row max: tree + half-exchange (order-agnostic) ----
                float t0, t1;
                t0 = fmaxf(s[0], s[1]);   t1 = fmaxf(s[2], s[3]);   t0 = fmaxf(t0, t1);
                t1 = fmaxf(s[4], s[5]);   t1 = fmaxf(t1, fmaxf(s[6], s[7]));
                float t2 = fmaxf(fmaxf(s[8], s[9]), fmaxf(s[10], s[11]));
                float t3 = fmaxf(fmaxf(s[12], s[13]), fmaxf(s[14], s[15]));
                float mx = fmaxf(fmaxf(t0, t1), fmaxf(t2, t3));
                {
                    unsigned int r0, r1;
                    halfswap(__float_as_uint(mx), r0, r1);
                    mx = fmaxf(__uint_as_float(r0), __uint_as_float(r1));
                }
                const float mnew = fmaxf(m, mx);
                const float corr = ex2(m - mnew);
                m = mnew;
                // ---- P = 2^(S - m), row sum ----
                float rs = 0.0f;
#pragma unroll
                for (int i = 0; i < 16; ++i) {
                    float pv = ex2(s[i] - mnew);
                    s[i] = pv;
                    rs += pv;
                }
                {
                    unsigned int r0, r1;
                    halfswap(__float_as_uint(rs), r0, r1);
                    rs = __uint_as_float(r0) + __uint_as_float(r1);
                }
                lsum = lsum * corr + rs;
#pragma unroll
                for (int i = 0; i < 16; ++i) { o0[i] *= corr; o1[i] *= corr; }
                // ---- pack P -> B-fragments (cvt_pk; partner via r0^r1^own) ----
                unsigned int cc[8], pc[8];
#pragma unroll
                for (int i = 0; i < 8; ++i) cc[i] = cvtpk_bf16(s[2 * i], s[2 * i + 1]);
#pragma unroll
                for (int i = 0; i < 8; ++i) {
                    unsigned int r0, r1;
                    halfswap(cc[i], r0, r1);
                    pc[i] = r0 ^ r1 ^ cc[i];         // partner word, any convention
                }
                u32x4 w0, w1;
                w0[0] = hi ? pc[2] : cc[0]; w0[1] = hi ? pc[3] : cc[1];
                w0[2] = hi ? cc[2] : pc[0]; w0[3] = hi ? cc[3] : pc[1];
                w1[0] = hi ? pc[6] : cc[4]; w1[1] = hi ? pc[7] : cc[5];
                w1[2] = hi ? cc[6] : pc[4]; w1[3] = hi ? cc[7] : pc[5];
                s16x8 pb0 = __builtin_bit_cast(s16x8, w0);
                s16x8 pb1 = __builtin_bit_cast(s16x8, w1);
                // ---- O^T += V^T P^T ----
                __builtin_amdgcn_s_setprio(1);
                o0 = mfma32(vf00, pb0, o0);
                o0 = mfma32(vf01, pb1, o0);
                o1 = mfma32(vf10, pb0, o1);
                o1 = mfma32(vf11, pb1, o1);
                __builtin_amdgcn_s_setprio(0);
            }
        }

        // ---- cascade combine: 16 -> 8 -> 4 -> 1 ----
        if (w >= 8) PUBLISH(w - 8);
        __syncthreads();
        if (w < 8) MERGE(w, w + 8);
        __syncthreads();
        if (w >= 4 && w < 8) PUBLISH(w - 4);
        __syncthreads();
        if (w < 4) { MERGE(w, w + 4); PUBLISH(w); }
        __syncthreads();
        // ---- final: 1024 threads, 2 outputs each ----
        {
            const int qq = (int)threadIdx.x >> 5;
            const int dd = ((int)threadIdx.x & 31) * 2;
            float M = -1e30f;
#pragma unroll
            for (int ww = 0; ww < 4; ++ww) M = fmaxf(M, sml[ww][0][qq]);
            float L = 0.0f, O0 = 0.0f, O1 = 0.0f;
#pragma unroll
            for (int ww = 0; ww < 4; ++ww) {
                float e = ex2(sml[ww][0][qq] - M);
                L += sml[ww][1][qq] * e;
                O0 += solds[ww][qq][dd] * e;
                O1 += solds[ww][qq][dd + 1] * e;
            }
            f32x2 res; res[0] = O0 / L; res[1] = O1 / L;
            *(f32x2*)(out + ((size_t)(b * SEQ_T + q0 + qq)) * 64 + dd) = res;
        }
        __syncthreads();                             // solds reused by next half
    }
#undef PUBLISH
#undef MERGE
}

// ---------------------------------------------------------------------------
extern "C" void kernel_launch(void* const* d_in, const int* in_sizes, int n_in,
                              void* d_out, int out_size, void* d_ws, size_t ws_size,
                              hipStream_t stream) {
    const float* x  = (const float*)d_in[0];
    const float* wq = (const float*)d_in[1];
    const float* bq = (const float*)d_in[2];
    const float* wk = (const float*)d_in[3];
    const float* bk = (const float*)d_in[4];
    const float* wv = (const float*)d_in[5];
    const float* bv = (const float*)d_in[6];
    float* out = (float*)d_out;

    char* ws = (char*)d_ws;
    unsigned short* wT    = (unsigned short*)(ws);                       // 384 KiB
    unsigned short* q_ws  = (unsigned short*)(ws + 393216);              // 2 MiB
    unsigned short* k_ws  = (unsigned short*)(ws + 393216 + 2097152);    // 2 MiB (tiled)
    unsigned short* vT_ws = (unsigned short*)(ws + 393216 + 2 * 2097152);// 2 MiB (tiled)

    wconv_kernel<<<dim3(768), dim3(256), 0, stream>>>(wq, wk, wv, wT);
    qkv_kernel<<<dim3(512), dim3(256), 0, stream>>>(x, bq, bk, bv, wT, q_ws, k_ws, vT_ws);
    attn_kernel<<<dim3(256), dim3(1024), 0, stream>>>(q_ws, k_ws, vT_ws, out);
}